// Round 2
// baseline (804.468 us; speedup 1.0000x reference)
//
#include <hip/hip_runtime.h>

// ElectrostaticEnergyLayer: per-pair shielded/switched Coulomb energy,
// scatter-added to atoms by idx_i.
//
// R1 insight: default atomicAdd (agent scope) executes memory-side on MI355X
// (WRITE_SIZE showed 32 B/atomic leaving TCC). Fix: 8 per-XCD replicas in ws,
// workgroup-scope atomics that execute in the XCD-local L2 (replica stays
// resident: 1 MB replica vs 4 MB L2/XCD), then an 8-way reduce kernel.

#define KEHALF 7.199822675975274f
#define NREP 8

__global__ __launch_bounds__(256) void ee_pair_priv(
    const float* __restrict__ Dij,
    const float* __restrict__ Qa,
    const int*   __restrict__ idx_i,
    const int*   __restrict__ idx_j,
    float*       __restrict__ reps,
    int P, int nAtoms)
{
    // Which XCD is this block on? (wave-uniform; blocks never migrate XCDs)
    int xcc;
    asm("s_getreg_b32 %0, hwreg(HW_REG_XCC_ID, 0, 4)" : "=s"(xcc));
    float* rep = reps + (size_t)(xcc & (NREP - 1)) * (size_t)nAtoms;

    long base = ((long)blockIdx.x * blockDim.x + threadIdx.x) * 4;
    if (base >= P) return;

    float4 d4 = *reinterpret_cast<const float4*>(Dij + base);
    int4   i4 = *reinterpret_cast<const int4*>(idx_i + base);
    int4   j4 = *reinterpret_cast<const int4*>(idx_j + base);

    float D[4]  = {d4.x, d4.y, d4.z, d4.w};
    int   ii[4] = {i4.x, i4.y, i4.z, i4.w};
    int   jj[4] = {j4.x, j4.y, j4.z, j4.w};

#pragma unroll
    for (int k = 0; k < 4; ++k) {
        float d = D[k];
        if (d > 10.0f) continue;   // reference zeroes beyond LR cutoff

        float Qi = Qa[ii[k]];
        float Qj = Qa[jj[k]];

        float dsh = sqrtf(d * d + 1.0f);
        float x   = 0.5f * d;               // x = D / (SR_CUTOFF/2), SR/2 = 2.0
        float sw  = (x < 1.0f) ? 1.0f - x * x * x * (x * (6.0f * x - 15.0f) + 10.0f)
                               : 0.0f;

        float Eo = 1.0f / d   + d   * 0.01f - 0.2f;
        float Es = 1.0f / dsh + dsh * 0.01f - 0.2f;

        float e = KEHALF * Qi * Qj * (sw * Es + (1.0f - sw) * Eo);

        // Workgroup-scope relaxed atomic: executes in the XCD-local L2 (no
        // device-scope bypass). Safe because replica `xcc` is only ever
        // touched by blocks resident on XCD `xcc`, and global atomics are
        // performed at L2, never cached in L1.
        __hip_atomic_fetch_add(rep + ii[k], e, __ATOMIC_RELAXED,
                               __HIP_MEMORY_SCOPE_WORKGROUP);
    }
}

// Fallback path (ws too small): direct device-scope atomics into out.
__global__ __launch_bounds__(256) void ee_pair_direct(
    const float* __restrict__ Dij,
    const float* __restrict__ Qa,
    const int*   __restrict__ idx_i,
    const int*   __restrict__ idx_j,
    float*       __restrict__ out,
    int P)
{
    long base = ((long)blockIdx.x * blockDim.x + threadIdx.x) * 4;
    if (base >= P) return;
    float4 d4 = *reinterpret_cast<const float4*>(Dij + base);
    int4   i4 = *reinterpret_cast<const int4*>(idx_i + base);
    int4   j4 = *reinterpret_cast<const int4*>(idx_j + base);
    float D[4]  = {d4.x, d4.y, d4.z, d4.w};
    int   ii[4] = {i4.x, i4.y, i4.z, i4.w};
    int   jj[4] = {j4.x, j4.y, j4.z, j4.w};
#pragma unroll
    for (int k = 0; k < 4; ++k) {
        float d = D[k];
        if (d > 10.0f) continue;
        float Qi = Qa[ii[k]], Qj = Qa[jj[k]];
        float dsh = sqrtf(d * d + 1.0f);
        float x = 0.5f * d;
        float sw = (x < 1.0f) ? 1.0f - x * x * x * (x * (6.0f * x - 15.0f) + 10.0f) : 0.0f;
        float Eo = 1.0f / d + d * 0.01f - 0.2f;
        float Es = 1.0f / dsh + dsh * 0.01f - 0.2f;
        float e = KEHALF * Qi * Qj * (sw * Es + (1.0f - sw) * Eo);
        atomicAdd(out + ii[k], e);
    }
}

// Sum the 8 replicas into out. nAtoms is a multiple of 4 (262144).
__global__ __launch_bounds__(256) void ee_reduce(
    const float* __restrict__ reps, float* __restrict__ out, int nAtoms)
{
    int n4 = nAtoms >> 2;
    int q = blockIdx.x * blockDim.x + threadIdx.x;
    if (q >= n4) return;
    const float4* r4 = reinterpret_cast<const float4*>(reps);
    float4 s = r4[q];
#pragma unroll
    for (int r = 1; r < NREP; ++r) {
        float4 t = r4[(size_t)r * n4 + q];
        s.x += t.x; s.y += t.y; s.z += t.z; s.w += t.w;
    }
    reinterpret_cast<float4*>(out)[q] = s;
}

extern "C" void kernel_launch(void* const* d_in, const int* in_sizes, int n_in,
                              void* d_out, int out_size, void* d_ws, size_t ws_size,
                              hipStream_t stream) {
    const float* Dij   = (const float*)d_in[0];
    const float* Qa    = (const float*)d_in[1];
    const int*   idx_i = (const int*)d_in[2];
    const int*   idx_j = (const int*)d_in[3];
    float*       out   = (float*)d_out;

    int P      = in_sizes[0];
    int nAtoms = in_sizes[1];

    int threads = (P + 3) / 4;
    int block = 256;
    int grid = (threads + block - 1) / block;

    size_t repBytes = (size_t)NREP * (size_t)nAtoms * sizeof(float);

    if (ws_size >= repBytes && (nAtoms & 3) == 0) {
        float* reps = (float*)d_ws;
        hipMemsetAsync(reps, 0, repBytes, stream);   // ws is re-poisoned 0xAA each launch
        ee_pair_priv<<<grid, block, 0, stream>>>(Dij, Qa, idx_i, idx_j, reps, P, nAtoms);
        int n4 = nAtoms >> 2;
        int rgrid = (n4 + block - 1) / block;
        ee_reduce<<<rgrid, block, 0, stream>>>(reps, out, nAtoms);
    } else {
        hipMemsetAsync(out, 0, (size_t)out_size * sizeof(float), stream);
        ee_pair_direct<<<grid, block, 0, stream>>>(Dij, Qa, idx_i, idx_j, out, P);
    }
}

// Round 3
// 659.618 us; speedup vs baseline: 1.2196x; 1.2196x over previous
//
#include <hip/hip_runtime.h>

// ElectrostaticEnergyLayer: per-pair shielded/switched Coulomb energy,
// scatter-added to atoms by idx_i.
//
// R2 post-mortem: float atomicAdd (any scope) = 32 B/atomic past TCC,
// 20.5 G atomics/s — suspected CAS-loop lowering for fp32. R3: accumulate in
// fixed-point int32 (scale 2^22) with native no-return global_atomic_add_u32,
// then convert to float. |e| <= ~13 (shielding caps radial factor at 0.81),
// per-atom sums O(30) << 512 = int32 range at this scale; quantization
// 1.2e-7/pair vs 0.33 threshold.

#define KEHALF 7.199822675975274f
#define FP_SCALE 4194304.0f         // 2^22
#define FP_INV   (1.0f / 4194304.0f)

__global__ __launch_bounds__(256) void ee_pair_fix(
    const float* __restrict__ Dij,
    const float* __restrict__ Qa,
    const int*   __restrict__ idx_i,
    const int*   __restrict__ idx_j,
    int*         __restrict__ acc,
    int P)
{
    long base = ((long)blockIdx.x * blockDim.x + threadIdx.x) * 4;
    if (base >= P) return;

    float4 d4 = *reinterpret_cast<const float4*>(Dij + base);
    int4   i4 = *reinterpret_cast<const int4*>(idx_i + base);
    int4   j4 = *reinterpret_cast<const int4*>(idx_j + base);

    float D[4]  = {d4.x, d4.y, d4.z, d4.w};
    int   ii[4] = {i4.x, i4.y, i4.z, i4.w};
    int   jj[4] = {j4.x, j4.y, j4.z, j4.w};

#pragma unroll
    for (int k = 0; k < 4; ++k) {
        float d = D[k];
        if (d > 10.0f) continue;   // reference zeroes beyond LR cutoff

        float Qi = Qa[ii[k]];
        float Qj = Qa[jj[k]];

        float dsh = sqrtf(d * d + 1.0f);
        float x   = 0.5f * d;               // x = D / (SR_CUTOFF/2), SR/2 = 2.0
        float sw  = (x < 1.0f) ? 1.0f - x * x * x * (x * (6.0f * x - 15.0f) + 10.0f)
                               : 0.0f;

        float Eo = 1.0f / d   + d   * 0.01f - 0.2f;
        float Es = 1.0f / dsh + dsh * 0.01f - 0.2f;

        float e = KEHALF * Qi * Qj * (sw * Es + (1.0f - sw) * Eo);

        int v = __float2int_rn(e * FP_SCALE);
        atomicAdd(acc + ii[k], v);   // native no-return global_atomic_add_u32
    }
}

// Convert fixed-point accumulators to float output.
__global__ __launch_bounds__(256) void ee_convert(
    const int* __restrict__ acc, float* __restrict__ out, int nAtoms)
{
    int n4 = nAtoms >> 2;
    int q = blockIdx.x * blockDim.x + threadIdx.x;
    if (q >= n4) return;
    int4 a = reinterpret_cast<const int4*>(acc)[q];
    float4 o;
    o.x = (float)a.x * FP_INV;
    o.y = (float)a.y * FP_INV;
    o.z = (float)a.z * FP_INV;
    o.w = (float)a.w * FP_INV;
    reinterpret_cast<float4*>(out)[q] = o;
}

// Fallback (ws too small or nAtoms not /4): direct float atomics.
__global__ __launch_bounds__(256) void ee_pair_direct(
    const float* __restrict__ Dij,
    const float* __restrict__ Qa,
    const int*   __restrict__ idx_i,
    const int*   __restrict__ idx_j,
    float*       __restrict__ out,
    int P)
{
    long t = (long)blockIdx.x * blockDim.x + threadIdx.x;
    if (t >= P) return;
    float d = Dij[t];
    if (d > 10.0f) return;
    float Qi = Qa[idx_i[t]], Qj = Qa[idx_j[t]];
    float dsh = sqrtf(d * d + 1.0f);
    float x = 0.5f * d;
    float sw = (x < 1.0f) ? 1.0f - x * x * x * (x * (6.0f * x - 15.0f) + 10.0f) : 0.0f;
    float Eo = 1.0f / d + d * 0.01f - 0.2f;
    float Es = 1.0f / dsh + dsh * 0.01f - 0.2f;
    atomicAdd(out + idx_i[t], KEHALF * Qi * Qj * (sw * Es + (1.0f - sw) * Eo));
}

extern "C" void kernel_launch(void* const* d_in, const int* in_sizes, int n_in,
                              void* d_out, int out_size, void* d_ws, size_t ws_size,
                              hipStream_t stream) {
    const float* Dij   = (const float*)d_in[0];
    const float* Qa    = (const float*)d_in[1];
    const int*   idx_i = (const int*)d_in[2];
    const int*   idx_j = (const int*)d_in[3];
    float*       out   = (float*)d_out;

    int P      = in_sizes[0];
    int nAtoms = in_sizes[1];

    int block = 256;
    size_t accBytes = (size_t)nAtoms * sizeof(int);

    if (ws_size >= accBytes && (nAtoms & 3) == 0 && (P & 3) == 0) {
        int* acc = (int*)d_ws;
        hipMemsetAsync(acc, 0, accBytes, stream);
        int threads = P / 4;
        int grid = (threads + block - 1) / block;
        ee_pair_fix<<<grid, block, 0, stream>>>(Dij, Qa, idx_i, idx_j, acc, P);
        int n4 = nAtoms >> 2;
        int cgrid = (n4 + block - 1) / block;
        ee_convert<<<cgrid, block, 0, stream>>>(acc, out, nAtoms);
    } else {
        hipMemsetAsync(out, 0, (size_t)out_size * sizeof(float), stream);
        int grid = (P + block - 1) / block;
        ee_pair_direct<<<grid, block, 0, stream>>>(Dij, Qa, idx_i, idx_j, out, P);
    }
}

// Round 4
// 443.228 us; speedup vs baseline: 1.8150x; 1.4882x over previous
//
#include <hip/hip_runtime.h>

// ElectrostaticEnergyLayer: per-pair shielded/switched Coulomb energy,
// scatter-added to atoms by idx_i.
//
// R3 post-mortem: WRITE_SIZE identical (432 MB = 32 B x 13.85M) for float AND
// int atomics, any scope => global atomics are memory-side (TCC->EA), capped
// ~26 G/s. R4: remove per-pair global atomics entirely. Two-phase binning:
//   P1: bin pairs into 1024 bucket regions (256 atoms each) as 4 B packed
//       (li<<24 | v24) fixed-point entries; per-block LDS histogram + one
//       cursor reservation per (block,bucket); plain stores (L2-merged).
//   P2: one block per bucket, LDS int accumulation (native ds_add_u32),
//       write 256 floats. Int fixed point => associative => deterministic.

#define KEHALF 7.199822675975274f
#define NB   1024          // buckets (nAtoms/256)
#define CAP  16384         // entries per bucket region (mean ~13.5K, 24 sigma)
#define CURSTRIDE 16       // pad cursors to 64 B to spread EA channels
#define VSCALE 524288.0f   // 2^19 fixed-point scale; |v| <= ~5.8e6 < 2^23
#define VINV   (1.0f / 524288.0f)
#define KPT  16            // pairs per thread in phase 1

__device__ __forceinline__ float pair_energy(float d, float Qi, float Qj) {
    float dsh = sqrtf(d * d + 1.0f);
    float x   = 0.5f * d;               // x = D / (SR_CUTOFF/2), SR/2 = 2.0
    float sw  = (x < 1.0f) ? 1.0f - x * x * x * (x * (6.0f * x - 15.0f) + 10.0f)
                           : 0.0f;
    float Eo = 1.0f / d   + d   * 0.01f - 0.2f;
    float Es = 1.0f / dsh + dsh * 0.01f - 0.2f;
    return KEHALF * Qi * Qj * (sw * Es + (1.0f - sw) * Eo);
}

// ---------------- Phase 1: bin pairs into bucket regions ----------------
__global__ __launch_bounds__(1024) void ee_bin(
    const float* __restrict__ Dij,
    const float* __restrict__ Qa,
    const int*   __restrict__ idx_i,
    const int*   __restrict__ idx_j,
    unsigned int* __restrict__ list,    // NB * CAP packed entries
    unsigned int* __restrict__ gcur,    // NB cursors, stride CURSTRIDE
    int P)
{
    __shared__ int cnt[NB];
    __shared__ int gofs[NB];
    __shared__ int lcur[NB];
    int tid = threadIdx.x;
    cnt[tid] = 0;
    lcur[tid] = 0;
    __syncthreads();

    long base = ((long)blockIdx.x * blockDim.x + tid) * (long)KPT;

    unsigned int uval[KPT];
    int          ubkt[KPT];

#pragma unroll
    for (int g = 0; g < KPT / 4; ++g) {
        long o = base + g * 4;
        float4 d4 = *reinterpret_cast<const float4*>(Dij + o);
        int4   i4 = *reinterpret_cast<const int4*>(idx_i + o);
        int4   j4 = *reinterpret_cast<const int4*>(idx_j + o);
        float D[4]  = {d4.x, d4.y, d4.z, d4.w};
        int   II[4] = {i4.x, i4.y, i4.z, i4.w};
        int   JJ[4] = {j4.x, j4.y, j4.z, j4.w};
#pragma unroll
        for (int k = 0; k < 4; ++k) {
            int m = g * 4 + k;
            float d = D[k];
            if (d <= 10.0f) {
                float e = pair_energy(d, Qa[II[k]], Qa[JJ[k]]);
                int v = __float2int_rn(e * VSCALE);          // fits in 24 bits
                int b = II[k] >> 8;
                unsigned int li = (unsigned int)(II[k] & 255);
                uval[m] = (li << 24) | ((unsigned int)v & 0xFFFFFFu);
                ubkt[m] = b;
                atomicAdd(&cnt[b], 1);
            } else {
                ubkt[m] = -1;
                uval[m] = 0;
            }
        }
    }
    __syncthreads();

    // one global reservation per (block, bucket); blockDim == NB == 1024
    gofs[tid] = (int)atomicAdd(&gcur[tid * CURSTRIDE], (unsigned int)cnt[tid]);
    __syncthreads();

#pragma unroll
    for (int m = 0; m < KPT; ++m) {
        int b = ubkt[m];
        if (b >= 0) {
            int slot = atomicAdd(&lcur[b], 1);
            long gpos = (long)b * CAP + (long)(gofs[b] + slot);
            if (gofs[b] + slot < CAP)                       // statistical safety
                list[gpos] = uval[m];
        }
    }
}

// ---------------- Phase 2: per-bucket LDS accumulation ----------------
__global__ __launch_bounds__(256) void ee_acc(
    const unsigned int* __restrict__ list,
    const unsigned int* __restrict__ gcur,
    float* __restrict__ out)
{
    __shared__ int acc[256];
    int b = blockIdx.x;
    int t = threadIdx.x;
    acc[t] = 0;
    __syncthreads();

    int n = (int)gcur[b * CURSTRIDE];
    if (n > CAP) n = CAP;
    const unsigned int* lp = list + (long)b * CAP;
    for (int j = t; j < n; j += 256) {
        unsigned int u = lp[j];
        int li = (int)(u >> 24);
        int v  = ((int)(u << 8)) >> 8;    // sign-extend 24-bit payload
        atomicAdd(&acc[li], v);           // native ds_add_u32
    }
    __syncthreads();
    out[b * 256 + t] = (float)acc[t] * VINV;
}

// ---------------- Fallback A: int fixed-point global atomics (R3) --------
#define FP_SCALE 4194304.0f
#define FP_INV   (1.0f / 4194304.0f)

__global__ __launch_bounds__(256) void ee_pair_fix(
    const float* __restrict__ Dij,
    const float* __restrict__ Qa,
    const int*   __restrict__ idx_i,
    const int*   __restrict__ idx_j,
    int*         __restrict__ acc,
    int P)
{
    long base = ((long)blockIdx.x * blockDim.x + threadIdx.x) * 4;
    if (base >= P) return;
    float4 d4 = *reinterpret_cast<const float4*>(Dij + base);
    int4   i4 = *reinterpret_cast<const int4*>(idx_i + base);
    int4   j4 = *reinterpret_cast<const int4*>(idx_j + base);
    float D[4]  = {d4.x, d4.y, d4.z, d4.w};
    int   ii[4] = {i4.x, i4.y, i4.z, i4.w};
    int   jj[4] = {j4.x, j4.y, j4.z, j4.w};
#pragma unroll
    for (int k = 0; k < 4; ++k) {
        float d = D[k];
        if (d > 10.0f) continue;
        float e = pair_energy(d, Qa[ii[k]], Qa[jj[k]]);
        atomicAdd(acc + ii[k], __float2int_rn(e * FP_SCALE));
    }
}

__global__ __launch_bounds__(256) void ee_convert(
    const int* __restrict__ acc, float* __restrict__ out, int nAtoms)
{
    int n4 = nAtoms >> 2;
    int q = blockIdx.x * blockDim.x + threadIdx.x;
    if (q >= n4) return;
    int4 a = reinterpret_cast<const int4*>(acc)[q];
    float4 o;
    o.x = (float)a.x * FP_INV;
    o.y = (float)a.y * FP_INV;
    o.z = (float)a.z * FP_INV;
    o.w = (float)a.w * FP_INV;
    reinterpret_cast<float4*>(out)[q] = o;
}

// ---------------- Fallback B: direct float atomics ----------------
__global__ __launch_bounds__(256) void ee_pair_direct(
    const float* __restrict__ Dij,
    const float* __restrict__ Qa,
    const int*   __restrict__ idx_i,
    const int*   __restrict__ idx_j,
    float*       __restrict__ out,
    int P)
{
    long t = (long)blockIdx.x * blockDim.x + threadIdx.x;
    if (t >= P) return;
    float d = Dij[t];
    if (d > 10.0f) return;
    atomicAdd(out + idx_i[t], pair_energy(d, Qa[idx_i[t]], Qa[idx_j[t]]));
}

extern "C" void kernel_launch(void* const* d_in, const int* in_sizes, int n_in,
                              void* d_out, int out_size, void* d_ws, size_t ws_size,
                              hipStream_t stream) {
    const float* Dij   = (const float*)d_in[0];
    const float* Qa    = (const float*)d_in[1];
    const int*   idx_i = (const int*)d_in[2];
    const int*   idx_j = (const int*)d_in[3];
    float*       out   = (float*)d_out;

    int P      = in_sizes[0];
    int nAtoms = in_sizes[1];

    const int p1Block = 1024;
    const long chunk  = (long)p1Block * KPT;        // 16384 pairs per block

    size_t listBytes = (size_t)NB * CAP * sizeof(unsigned int);   // 64 MiB
    size_t curBytes  = (size_t)NB * CURSTRIDE * sizeof(unsigned int); // 64 KiB

    if (ws_size >= listBytes + curBytes &&
        nAtoms == NB * 256 && (P % chunk) == 0) {
        unsigned int* list = (unsigned int*)d_ws;
        unsigned int* gcur = (unsigned int*)((char*)d_ws + listBytes);
        hipMemsetAsync(gcur, 0, curBytes, stream);
        int grid1 = (int)(P / chunk);               // 1024
        ee_bin<<<grid1, p1Block, 0, stream>>>(Dij, Qa, idx_i, idx_j, list, gcur, P);
        ee_acc<<<NB, 256, 0, stream>>>(list, gcur, out);   // writes every output
    } else if (ws_size >= (size_t)nAtoms * sizeof(int) &&
               (nAtoms & 3) == 0 && (P & 3) == 0) {
        int* acc = (int*)d_ws;
        hipMemsetAsync(acc, 0, (size_t)nAtoms * sizeof(int), stream);
        int grid = (P / 4 + 255) / 256;
        ee_pair_fix<<<grid, 256, 0, stream>>>(Dij, Qa, idx_i, idx_j, acc, P);
        ee_convert<<<(nAtoms / 4 + 255) / 256, 256, 0, stream>>>(acc, out, nAtoms);
    } else {
        hipMemsetAsync(out, 0, (size_t)out_size * sizeof(float), stream);
        int grid = (P + 255) / 256;
        ee_pair_direct<<<grid, 256, 0, stream>>>(Dij, Qa, idx_i, idx_j, out, P);
    }
}

// Round 5
// 407.261 us; speedup vs baseline: 1.9753x; 1.0883x over previous
//
#include <hip/hip_runtime.h>

// ElectrostaticEnergyLayer: per-pair shielded/switched Coulomb energy,
// scatter-added to atoms by idx_i.
//
// R4 post-mortem: ee_bin was writeback-bound — WRITE_SIZE 310 MB vs 55 MB
// payload because 54 B runs shared 64 B L2 lines across blocks/XCDs.
// R5: 128 buckets (runs ~512 B), cursor reservations padded to 64 B and
// zero-filled by the owning block => every list line is full-line,
// single-writer, aligned. Entry = (li<<21)|v21, fixed point scale 2^16.
// Phase 2: 4 chunks/bucket, 8 KB LDS int accumulators (ds_add_u32) ->
// int partials; Phase 3: reduce partials -> float out. Int accumulation is
// associative => deterministic across graph replays.

#define KEHALF 7.199822675975274f
#define NB    128            // buckets
#define BSH   11             // atoms per bucket = 2048
#define BMASK 2047
#define CAP   122880         // entries per bucket region (mean ~116K w/ pad)
#define CURSTRIDE 16         // cursor padding: 64 B apart
#define SCH   4              // phase-2 chunks per bucket
#define VSCALE 65536.0f      // 2^16; |v| <= ~760K < 2^20 (21-bit signed)
#define VINV   (1.0f / 65536.0f)
#define KPT   16             // pairs per thread in phase 1
#define P1B   1024           // phase-1 block size

__device__ __forceinline__ float pair_energy(float d, float Qi, float Qj) {
    float dsh = sqrtf(d * d + 1.0f);
    float x   = 0.5f * d;               // x = D / (SR_CUTOFF/2), SR/2 = 2.0
    float sw  = (x < 1.0f) ? 1.0f - x * x * x * (x * (6.0f * x - 15.0f) + 10.0f)
                           : 0.0f;
    float Eo = 1.0f / d   + d   * 0.01f - 0.2f;
    float Es = 1.0f / dsh + dsh * 0.01f - 0.2f;
    return KEHALF * Qi * Qj * (sw * Es + (1.0f - sw) * Eo);
}

// ---------------- Phase 1: bin pairs into bucket regions ----------------
__global__ __launch_bounds__(P1B) void ee_bin(
    const float* __restrict__ Dij,
    const float* __restrict__ Qa,
    const int*   __restrict__ idx_i,
    const int*   __restrict__ idx_j,
    unsigned int* __restrict__ list,    // NB * CAP packed entries
    unsigned int* __restrict__ gcur,    // NB cursors, stride CURSTRIDE
    int P)
{
    __shared__ int cnt[NB];
    __shared__ int gofs[NB];
    __shared__ int lcur[NB];
    int tid = threadIdx.x;
    if (tid < NB) { cnt[tid] = 0; lcur[tid] = 0; }
    __syncthreads();

    long base = ((long)blockIdx.x * P1B + tid) * (long)KPT;

    unsigned int uval[KPT];
    int          ubkt[KPT];

#pragma unroll
    for (int g = 0; g < KPT / 4; ++g) {
        long o = base + g * 4;
        float4 d4 = *reinterpret_cast<const float4*>(Dij + o);
        int4   i4 = *reinterpret_cast<const int4*>(idx_i + o);
        int4   j4 = *reinterpret_cast<const int4*>(idx_j + o);
        float D[4]  = {d4.x, d4.y, d4.z, d4.w};
        int   II[4] = {i4.x, i4.y, i4.z, i4.w};
        int   JJ[4] = {j4.x, j4.y, j4.z, j4.w};
#pragma unroll
        for (int k = 0; k < 4; ++k) {
            int m = g * 4 + k;
            float d = D[k];
            if (d <= 10.0f) {
                float e = pair_energy(d, Qa[II[k]], Qa[JJ[k]]);
                int v = __float2int_rn(e * VSCALE);          // 21-bit signed
                int b = II[k] >> BSH;
                unsigned int li = (unsigned int)(II[k] & BMASK);
                uval[m] = (li << 21) | ((unsigned int)v & 0x1FFFFFu);
                ubkt[m] = b;
                atomicAdd(&cnt[b], 1);
            } else {
                ubkt[m] = -1;
                uval[m] = 0;
            }
        }
    }
    __syncthreads();

    // one padded (64 B-multiple) reservation per (block, bucket)
    if (tid < NB) {
        int padded = (cnt[tid] + 15) & ~15;
        gofs[tid] = (int)atomicAdd(&gcur[tid * CURSTRIDE], (unsigned int)padded);
    }
    __syncthreads();

#pragma unroll
    for (int m = 0; m < KPT; ++m) {
        int b = ubkt[m];
        if (b >= 0) {
            int slot = atomicAdd(&lcur[b], 1);
            int pos = gofs[b] + slot;
            if (pos < CAP)                              // statistical safety
                list[(long)b * CAP + pos] = uval[m];
        }
    }

    // zero-fill the pad so every reserved line is fully written by this block
    if (tid < NB) {
        int c = cnt[tid];
        int padded = (c + 15) & ~15;
        long rb = (long)tid * CAP;
        for (int j = c; j < padded; ++j) {
            int pos = gofs[tid] + j;
            if (pos < CAP) list[rb + pos] = 0u;          // (li=0, v=0): adds 0
        }
    }
}

// ---------------- Phase 2: per-bucket-chunk LDS accumulation ----------------
__global__ __launch_bounds__(256) void ee_acc(
    const unsigned int* __restrict__ list,
    const unsigned int* __restrict__ gcur,
    int* __restrict__ partials)          // [NB*SCH][2048]
{
    __shared__ int acc[1 << BSH];
    int b = blockIdx.x / SCH;
    int s = blockIdx.x % SCH;
    int t = threadIdx.x;
#pragma unroll
    for (int r = 0; r < (1 << BSH) / 256; ++r) acc[t + r * 256] = 0;
    __syncthreads();

    int n = (int)gcur[b * CURSTRIDE];    // padded total, multiple of 16
    if (n > CAP) n = CAP;
    int nq = n >> 2;                     // uint4 count
    int per = ((nq + SCH - 1) / SCH + 3) & ~3;
    int q0 = s * per;
    int q1 = q0 + per; if (q1 > nq) q1 = nq;

    const uint4* lp4 = reinterpret_cast<const uint4*>(list + (long)b * CAP);
    for (int q = q0 + t; q < q1; q += 256) {
        uint4 u4 = lp4[q];
        unsigned int us[4] = {u4.x, u4.y, u4.z, u4.w};
#pragma unroll
        for (int k = 0; k < 4; ++k) {
            unsigned int u = us[k];
            int li = (int)(u >> 21);
            int v  = ((int)(u << 11)) >> 11;   // sign-extend 21-bit payload
            atomicAdd(&acc[li], v);            // native ds_add_u32
        }
    }
    __syncthreads();

    int* pp = partials + ((long)b * SCH + s) * (1 << BSH);
#pragma unroll
    for (int r = 0; r < (1 << BSH) / 256; ++r) pp[t + r * 256] = acc[t + r * 256];
}

// ---------------- Phase 3: reduce partials -> float out ----------------
__global__ __launch_bounds__(256) void ee_final(
    const int* __restrict__ partials, float* __restrict__ out, int nAtoms)
{
    int q = blockIdx.x * blockDim.x + threadIdx.x;      // one int4 per thread
    int n4 = nAtoms >> 2;
    if (q >= n4) return;
    int a0 = q << 2;
    int b  = a0 >> BSH;
    int li = a0 & BMASK;
    long base = (long)b * SCH * (1 << BSH) + li;
    int4 s = {0, 0, 0, 0};
#pragma unroll
    for (int r = 0; r < SCH; ++r) {
        int4 p = *reinterpret_cast<const int4*>(partials + base + (long)r * (1 << BSH));
        s.x += p.x; s.y += p.y; s.z += p.z; s.w += p.w;
    }
    float4 o;
    o.x = (float)s.x * VINV;
    o.y = (float)s.y * VINV;
    o.z = (float)s.z * VINV;
    o.w = (float)s.w * VINV;
    reinterpret_cast<float4*>(out)[q] = o;
}

// ---------------- Fallback: int fixed-point global atomics (R3) --------
#define FP_SCALE 4194304.0f
#define FP_INV   (1.0f / 4194304.0f)

__global__ __launch_bounds__(256) void ee_pair_fix(
    const float* __restrict__ Dij,
    const float* __restrict__ Qa,
    const int*   __restrict__ idx_i,
    const int*   __restrict__ idx_j,
    int*         __restrict__ acc,
    int P)
{
    long base = ((long)blockIdx.x * blockDim.x + threadIdx.x) * 4;
    if (base >= P) return;
    float4 d4 = *reinterpret_cast<const float4*>(Dij + base);
    int4   i4 = *reinterpret_cast<const int4*>(idx_i + base);
    int4   j4 = *reinterpret_cast<const int4*>(idx_j + base);
    float D[4]  = {d4.x, d4.y, d4.z, d4.w};
    int   ii[4] = {i4.x, i4.y, i4.z, i4.w};
    int   jj[4] = {j4.x, j4.y, j4.z, j4.w};
#pragma unroll
    for (int k = 0; k < 4; ++k) {
        float d = D[k];
        if (d > 10.0f) continue;
        float e = pair_energy(d, Qa[ii[k]], Qa[jj[k]]);
        atomicAdd(acc + ii[k], __float2int_rn(e * FP_SCALE));
    }
}

__global__ __launch_bounds__(256) void ee_convert(
    const int* __restrict__ acc, float* __restrict__ out, int nAtoms)
{
    int n4 = nAtoms >> 2;
    int q = blockIdx.x * blockDim.x + threadIdx.x;
    if (q >= n4) return;
    int4 a = reinterpret_cast<const int4*>(acc)[q];
    float4 o;
    o.x = (float)a.x * FP_INV;
    o.y = (float)a.y * FP_INV;
    o.z = (float)a.z * FP_INV;
    o.w = (float)a.w * FP_INV;
    reinterpret_cast<float4*>(out)[q] = o;
}

__global__ __launch_bounds__(256) void ee_pair_direct(
    const float* __restrict__ Dij,
    const float* __restrict__ Qa,
    const int*   __restrict__ idx_i,
    const int*   __restrict__ idx_j,
    float*       __restrict__ out,
    int P)
{
    long t = (long)blockIdx.x * blockDim.x + threadIdx.x;
    if (t >= P) return;
    float d = Dij[t];
    if (d > 10.0f) return;
    atomicAdd(out + idx_i[t], pair_energy(d, Qa[idx_i[t]], Qa[idx_j[t]]));
}

extern "C" void kernel_launch(void* const* d_in, const int* in_sizes, int n_in,
                              void* d_out, int out_size, void* d_ws, size_t ws_size,
                              hipStream_t stream) {
    const float* Dij   = (const float*)d_in[0];
    const float* Qa    = (const float*)d_in[1];
    const int*   idx_i = (const int*)d_in[2];
    const int*   idx_j = (const int*)d_in[3];
    float*       out   = (float*)d_out;

    int P      = in_sizes[0];
    int nAtoms = in_sizes[1];

    const long chunk = (long)P1B * KPT;                       // 16384 pairs
    size_t listBytes = (size_t)NB * CAP * sizeof(unsigned int);       // 60 MiB
    size_t partBytes = (size_t)NB * SCH * (1 << BSH) * sizeof(int);   // 4 MiB
    size_t curBytes  = (size_t)NB * CURSTRIDE * sizeof(unsigned int); // 8 KiB

    if (ws_size >= listBytes + partBytes + curBytes &&
        nAtoms == NB * (1 << BSH) && (P % chunk) == 0) {
        unsigned int* list = (unsigned int*)d_ws;
        int*          part = (int*)((char*)d_ws + listBytes);
        unsigned int* gcur = (unsigned int*)((char*)d_ws + listBytes + partBytes);
        hipMemsetAsync(gcur, 0, curBytes, stream);
        int grid1 = (int)(P / chunk);                         // 1024
        ee_bin<<<grid1, P1B, 0, stream>>>(Dij, Qa, idx_i, idx_j, list, gcur, P);
        ee_acc<<<NB * SCH, 256, 0, stream>>>(list, gcur, part);
        ee_final<<<(nAtoms / 4 + 255) / 256, 256, 0, stream>>>(part, out, nAtoms);
    } else if (ws_size >= (size_t)nAtoms * sizeof(int) &&
               (nAtoms & 3) == 0 && (P & 3) == 0) {
        int* acc = (int*)d_ws;
        hipMemsetAsync(acc, 0, (size_t)nAtoms * sizeof(int), stream);
        int grid = (P / 4 + 255) / 256;
        ee_pair_fix<<<grid, 256, 0, stream>>>(Dij, Qa, idx_i, idx_j, acc, P);
        ee_convert<<<(nAtoms / 4 + 255) / 256, 256, 0, stream>>>(acc, out, nAtoms);
    } else {
        hipMemsetAsync(out, 0, (size_t)out_size * sizeof(float), stream);
        int grid = (P + 255) / 256;
        ee_pair_direct<<<grid, 256, 0, stream>>>(Dij, Qa, idx_i, idx_j, out, P);
    }
}

// Round 6
// 285.151 us; speedup vs baseline: 2.8212x; 1.4282x over previous
//
#include <hip/hip_runtime.h>

// ElectrostaticEnergyLayer: per-pair shielded/switched Coulomb energy,
// scatter-added to atoms by idx_i.
//
// R5 post-mortem: write side fixed (91 MB) but FETCH 401 MB — Qa gathers
// (Qi+Qj, 27.7M random 4 B) miss L2 because list write-through + streams
// evict the 1 MB table; plus TA serialization on 41M divergent lane-txns.
// R6: (1) deferred-Q: E_i = KEHALF*Qi*sum_j Qj*R(dij) — Qi gather removed,
// applied streaming in P3. (2) LDS-staged binning: per-block LDS buckets,
// coalesced full-line padded copy-out — no scattered global stores.
// Overflow (E~0.1/launch) spills as float atomic into out; P3 reads out
// before overwrite. Int fixed point (2^19) => deterministic.

#define KEHALF 7.199822675975274f
#define NB    128            // buckets
#define BSH   11             // atoms per bucket = 2048
#define BMASK 2047
#define CAP   126976         // entries per bucket region (list = 62 MiB)
#define CURSTRIDE 16         // cursors 64 B apart
#define SCH   2              // phase-2 chunks per bucket
#define SCAP  96             // LDS staging slots per bucket per block
#define VSCALE 524288.0f     // 2^19; |Qj*R| <= ~1.2 -> |v| < 2^20
#define VINV   (1.0f / 524288.0f)
#define P1B   512            // phase-1 block threads
#define P1PAIRS 8192         // pairs per phase-1 block (512 thr x 16)

// radial factor R(d): E = KEHALF * Qi * Qj * R(d)
__device__ __forceinline__ float radial(float d) {
    float dsh = sqrtf(d * d + 1.0f);
    float x   = 0.5f * d;               // x = D / (SR_CUTOFF/2), SR/2 = 2.0
    float sw  = (x < 1.0f) ? 1.0f - x * x * x * (x * (6.0f * x - 15.0f) + 10.0f)
                           : 0.0f;
    float Eo = 1.0f / d   + d   * 0.01f - 0.2f;
    float Es = 1.0f / dsh + dsh * 0.01f - 0.2f;
    return sw * Es + (1.0f - sw) * Eo;
}

// ---------------- Phase 1: LDS-staged binning ----------------
__global__ __launch_bounds__(P1B) void ee_bin(
    const float* __restrict__ Dij,
    const float* __restrict__ Qa,
    const int*   __restrict__ idx_i,
    const int*   __restrict__ idx_j,
    unsigned int* __restrict__ list,    // NB * CAP packed entries
    unsigned int* __restrict__ gcur,    // NB cursors, stride CURSTRIDE
    float*        __restrict__ out)     // spill target (pre-zeroed)
{
    __shared__ unsigned int stage[NB * SCAP];   // 48 KiB
    __shared__ int lcur[NB];
    __shared__ int gofs[NB];
    int tid = threadIdx.x;
    if (tid < NB) lcur[tid] = 0;
    __syncthreads();

    long blockBase = (long)blockIdx.x * P1PAIRS;

#pragma unroll
    for (int g = 0; g < 4; ++g) {
        long o = blockBase + ((long)(g * P1B + tid)) * 4;
        float4 d4 = *reinterpret_cast<const float4*>(Dij + o);
        int4   i4 = *reinterpret_cast<const int4*>(idx_i + o);
        int4   j4 = *reinterpret_cast<const int4*>(idx_j + o);
        float D[4]  = {d4.x, d4.y, d4.z, d4.w};
        int   II[4] = {i4.x, i4.y, i4.z, i4.w};
        int   JJ[4] = {j4.x, j4.y, j4.z, j4.w};
#pragma unroll
        for (int k = 0; k < 4; ++k) {
            float d = D[k];
            if (d <= 10.0f) {
                float w = Qa[JJ[k]] * radial(d);   // deferred Qi
                int v = __float2int_rn(w * VSCALE);
                int b  = II[k] >> BSH;
                int li = II[k] & BMASK;
                int slot = atomicAdd(&lcur[b], 1);
                if (slot < SCAP) {
                    stage[b * SCAP + slot] =
                        ((unsigned int)li << 21) | ((unsigned int)v & 0x1FFFFFu);
                } else {
                    // rare (E ~ 0.1/launch): spill full energy into out
                    atomicAdd(out + II[k], KEHALF * Qa[II[k]] * w);
                }
            }
        }
    }
    __syncthreads();

    // one padded (16-entry = 64 B multiple) reservation per (block, bucket)
    if (tid < NB) {
        int n = lcur[tid];
        if (n > SCAP) n = SCAP;
        lcur[tid] = n;                          // clamp for copy-out
        int padded = (n + 15) & ~15;
        gofs[tid] = (int)atomicAdd(&gcur[tid * CURSTRIDE], (unsigned int)padded);
    }
    __syncthreads();

    // coalesced copy-out: wave w handles buckets w, w+8, ...
    int wave = tid >> 6, lane = tid & 63;
    for (int b = wave; b < NB; b += (P1B / 64)) {
        int n = lcur[b];
        int padded = (n + 15) & ~15;
        int go = gofs[b];
        long rb = (long)b * CAP;
        for (int i = lane; i < padded; i += 64) {
            unsigned int val = (i < n) ? stage[b * SCAP + i] : 0u;  // pad adds 0
            int pos = go + i;
            if (pos < CAP)                       // statistical hard guard
                list[rb + pos] = val;
        }
    }
}

// ---------------- Phase 2: per-bucket-chunk LDS int accumulation ----------
__global__ __launch_bounds__(512) void ee_acc(
    const unsigned int* __restrict__ list,
    const unsigned int* __restrict__ gcur,
    int* __restrict__ partials)          // [NB*SCH][2048]
{
    __shared__ int acc[1 << BSH];
    int b = blockIdx.x / SCH;
    int s = blockIdx.x % SCH;
    int t = threadIdx.x;
#pragma unroll
    for (int r = 0; r < (1 << BSH) / 512; ++r) acc[t + r * 512] = 0;
    __syncthreads();

    int n = (int)gcur[b * CURSTRIDE];    // padded total, multiple of 16
    if (n > CAP) n = CAP;
    int nq = n >> 2;                     // uint4 count
    int per = (nq + SCH - 1) / SCH;
    int q0 = s * per;
    int q1 = q0 + per; if (q1 > nq) q1 = nq;

    const uint4* lp4 = reinterpret_cast<const uint4*>(list + (long)b * CAP);
    for (int q = q0 + t; q < q1; q += 512) {
        uint4 u4 = lp4[q];
        unsigned int us[4] = {u4.x, u4.y, u4.z, u4.w};
#pragma unroll
        for (int k = 0; k < 4; ++k) {
            unsigned int u = us[k];
            int li = (int)(u >> 21);
            int v  = ((int)(u << 11)) >> 11;   // sign-extend 21-bit payload
            atomicAdd(&acc[li], v);            // native ds_add_u32
        }
    }
    __syncthreads();

    int* pp = partials + ((long)b * SCH + s) * (1 << BSH);
#pragma unroll
    for (int r = 0; r < (1 << BSH) / 512; ++r) pp[t + r * 512] = acc[t + r * 512];
}

// ---------------- Phase 3: combine partials, apply KEHALF*Qi, add spill ----
__global__ __launch_bounds__(256) void ee_final(
    const int* __restrict__ partials,
    const float* __restrict__ Qa,
    float* __restrict__ out, int nAtoms)
{
    int q = blockIdx.x * blockDim.x + threadIdx.x;      // one int4 per thread
    int n4 = nAtoms >> 2;
    if (q >= n4) return;
    int a0 = q << 2;
    int b  = a0 >> BSH;
    int li = a0 & BMASK;
    long base = (long)(b * SCH) * (1 << BSH) + li;
    int4 s = {0, 0, 0, 0};
#pragma unroll
    for (int r = 0; r < SCH; ++r) {
        int4 p = *reinterpret_cast<const int4*>(partials + base + (long)r * (1 << BSH));
        s.x += p.x; s.y += p.y; s.z += p.z; s.w += p.w;
    }
    float4 qv = reinterpret_cast<const float4*>(Qa)[q];
    float4 sp = reinterpret_cast<const float4*>(out)[q];   // spill (or 0)
    float4 o;
    o.x = KEHALF * qv.x * ((float)s.x * VINV) + sp.x;
    o.y = KEHALF * qv.y * ((float)s.y * VINV) + sp.y;
    o.z = KEHALF * qv.z * ((float)s.z * VINV) + sp.z;
    o.w = KEHALF * qv.w * ((float)s.w * VINV) + sp.w;
    reinterpret_cast<float4*>(out)[q] = o;
}

// ---------------- Fallback: int fixed-point global atomics (R3) --------
#define FP_SCALE 4194304.0f
#define FP_INV   (1.0f / 4194304.0f)

__global__ __launch_bounds__(256) void ee_pair_fix(
    const float* __restrict__ Dij,
    const float* __restrict__ Qa,
    const int*   __restrict__ idx_i,
    const int*   __restrict__ idx_j,
    int*         __restrict__ acc,
    int P)
{
    long base = ((long)blockIdx.x * blockDim.x + threadIdx.x) * 4;
    if (base >= P) return;
    float4 d4 = *reinterpret_cast<const float4*>(Dij + base);
    int4   i4 = *reinterpret_cast<const int4*>(idx_i + base);
    int4   j4 = *reinterpret_cast<const int4*>(idx_j + base);
    float D[4]  = {d4.x, d4.y, d4.z, d4.w};
    int   ii[4] = {i4.x, i4.y, i4.z, i4.w};
    int   jj[4] = {j4.x, j4.y, j4.z, j4.w};
#pragma unroll
    for (int k = 0; k < 4; ++k) {
        float d = D[k];
        if (d > 10.0f) continue;
        float e = KEHALF * Qa[ii[k]] * Qa[jj[k]] * radial(d);
        atomicAdd(acc + ii[k], __float2int_rn(e * FP_SCALE));
    }
}

__global__ __launch_bounds__(256) void ee_convert(
    const int* __restrict__ acc, float* __restrict__ out, int nAtoms)
{
    int n4 = nAtoms >> 2;
    int q = blockIdx.x * blockDim.x + threadIdx.x;
    if (q >= n4) return;
    int4 a = reinterpret_cast<const int4*>(acc)[q];
    float4 o;
    o.x = (float)a.x * FP_INV;
    o.y = (float)a.y * FP_INV;
    o.z = (float)a.z * FP_INV;
    o.w = (float)a.w * FP_INV;
    reinterpret_cast<float4*>(out)[q] = o;
}

__global__ __launch_bounds__(256) void ee_pair_direct(
    const float* __restrict__ Dij,
    const float* __restrict__ Qa,
    const int*   __restrict__ idx_i,
    const int*   __restrict__ idx_j,
    float*       __restrict__ out,
    int P)
{
    long t = (long)blockIdx.x * blockDim.x + threadIdx.x;
    if (t >= P) return;
    float d = Dij[t];
    if (d > 10.0f) return;
    atomicAdd(out + idx_i[t], KEHALF * Qa[idx_i[t]] * Qa[idx_j[t]] * radial(d));
}

extern "C" void kernel_launch(void* const* d_in, const int* in_sizes, int n_in,
                              void* d_out, int out_size, void* d_ws, size_t ws_size,
                              hipStream_t stream) {
    const float* Dij   = (const float*)d_in[0];
    const float* Qa    = (const float*)d_in[1];
    const int*   idx_i = (const int*)d_in[2];
    const int*   idx_j = (const int*)d_in[3];
    float*       out   = (float*)d_out;

    int P      = in_sizes[0];
    int nAtoms = in_sizes[1];

    size_t listBytes = (size_t)NB * CAP * sizeof(unsigned int);          // 62 MiB
    size_t partBytes = (size_t)NB * SCH * (1 << BSH) * sizeof(int);      // 2 MiB
    size_t curBytes  = (size_t)NB * CURSTRIDE * sizeof(unsigned int);    // 8 KiB

    if (ws_size >= listBytes + partBytes + curBytes &&
        nAtoms == NB * (1 << BSH) && (P % P1PAIRS) == 0) {
        unsigned int* list = (unsigned int*)d_ws;
        int*          part = (int*)((char*)d_ws + listBytes);
        unsigned int* gcur = (unsigned int*)((char*)d_ws + listBytes + partBytes);
        hipMemsetAsync(gcur, 0, curBytes, stream);
        hipMemsetAsync(out, 0, (size_t)out_size * sizeof(float), stream); // spill base
        int grid1 = P / P1PAIRS;                                          // 2048
        ee_bin<<<grid1, P1B, 0, stream>>>(Dij, Qa, idx_i, idx_j, list, gcur, out);
        ee_acc<<<NB * SCH, 512, 0, stream>>>(list, gcur, part);
        ee_final<<<(nAtoms / 4 + 255) / 256, 256, 0, stream>>>(part, Qa, out, nAtoms);
    } else if (ws_size >= (size_t)nAtoms * sizeof(int) &&
               (nAtoms & 3) == 0 && (P & 3) == 0) {
        int* acc = (int*)d_ws;
        hipMemsetAsync(acc, 0, (size_t)nAtoms * sizeof(int), stream);
        int grid = (P / 4 + 255) / 256;
        ee_pair_fix<<<grid, 256, 0, stream>>>(Dij, Qa, idx_i, idx_j, acc, P);
        ee_convert<<<(nAtoms / 4 + 255) / 256, 256, 0, stream>>>(acc, out, nAtoms);
    } else {
        hipMemsetAsync(out, 0, (size_t)out_size * sizeof(float), stream);
        int grid = (P + 255) / 256;
        ee_pair_direct<<<grid, 256, 0, stream>>>(Dij, Qa, idx_i, idx_j, out, P);
    }
}